// Round 2
// baseline (2573.688 us; speedup 1.0000x reference)
//
#include <hip/hip_runtime.h>
#include <math.h>

typedef __bf16 bf16;
typedef float f32x4 __attribute__((ext_vector_type(4)));
typedef bf16 bf16x8 __attribute__((ext_vector_type(8)));
typedef bf16 bf16x2 __attribute__((ext_vector_type(2)));

// async global->LDS, 16B per lane; lds base must be wave-uniform
__device__ __forceinline__ void gll16(const void* g, void* l) {
    __builtin_amdgcn_global_load_lds(
        (const __attribute__((address_space(1))) void*)g,
        (__attribute__((address_space(3))) void*)l, 16, 0, 0);
}

// ---------------- fp32 -> bf16 convert (weights) ----------------
__global__ __launch_bounds__(256) void lam_cvt(const float* __restrict__ s,
                                               bf16* __restrict__ d, int n) {
    int i = (blockIdx.x * 256 + threadIdx.x) * 8;
    if (i >= n) return;
    float4 a = *(const float4*)(s + i);
    float4 b = *(const float4*)(s + i + 4);
    bf16x8 o;
    o[0] = (bf16)a.x; o[1] = (bf16)a.y; o[2] = (bf16)a.z; o[3] = (bf16)a.w;
    o[4] = (bf16)b.x; o[5] = (bf16)b.y; o[6] = (bf16)b.z; o[7] = (bf16)b.w;
    *(bf16x8*)(d + i) = o;
}

__global__ __launch_bounds__(256) void lam_packb(const float* __restrict__ q,
                                                 const float* __restrict__ k,
                                                 const float* __restrict__ v,
                                                 float* __restrict__ dst) {
    int i = blockIdx.x * 256 + threadIdx.x;
    if (i < 1024) dst[i] = q[i];
    else if (i < 2048) dst[i] = k[i - 1024];
    else if (i < 3072) dst[i] = v[i - 2048];
}

// ---------------- LayerNorm: one wave per 1024-elem row ----------------
template<bool FP32IN>
__global__ __launch_bounds__(256) void lam_ln(const void* __restrict__ Xv,
                                              const float* __restrict__ g,
                                              const float* __restrict__ bta,
                                              bf16* __restrict__ Y) {
    const int lane = threadIdx.x & 63;
    const long row = (long)blockIdx.x * 4 + (threadIdx.x >> 6);
    const long base = row * 1024 + lane * 16;
    float v[16];
    if (FP32IN) {
        const float4* p = (const float4*)((const float*)Xv + base);
        #pragma unroll
        for (int q = 0; q < 4; ++q) {
            float4 f = p[q];
            v[q*4+0]=f.x; v[q*4+1]=f.y; v[q*4+2]=f.z; v[q*4+3]=f.w;
        }
    } else {
        const bf16x8* p = (const bf16x8*)((const bf16*)Xv + base);
        #pragma unroll
        for (int q = 0; q < 2; ++q) {
            bf16x8 u = p[q];
            #pragma unroll
            for (int e = 0; e < 8; ++e) v[q*8+e] = (float)u[e];
        }
    }
    float s = 0.f;
    #pragma unroll
    for (int e = 0; e < 16; ++e) s += v[e];
    #pragma unroll
    for (int m = 32; m >= 1; m >>= 1) s += __shfl_xor(s, m);
    const float mean = s * (1.0f / 1024.0f);
    float vs = 0.f;
    #pragma unroll
    for (int e = 0; e < 16; ++e) { float d = v[e] - mean; vs += d * d; }
    #pragma unroll
    for (int m = 32; m >= 1; m >>= 1) vs += __shfl_xor(vs, m);
    const float rstd = rsqrtf(vs * (1.0f / 1024.0f) + 1e-5f);
    const int kb = lane * 16;
    float gg[16], bb[16];
    const float4* gp = (const float4*)(g + kb);
    const float4* bp = (const float4*)(bta + kb);
    #pragma unroll
    for (int q = 0; q < 4; ++q) {
        float4 a = gp[q], c = bp[q];
        gg[q*4+0]=a.x; gg[q*4+1]=a.y; gg[q*4+2]=a.z; gg[q*4+3]=a.w;
        bb[q*4+0]=c.x; bb[q*4+1]=c.y; bb[q*4+2]=c.z; bb[q*4+3]=c.w;
    }
    bf16x8 o0, o1;
    #pragma unroll
    for (int e = 0; e < 8; ++e) {
        o0[e] = (bf16)((v[e]   - mean) * rstd * gg[e]   + bb[e]);
        o1[e] = (bf16)((v[8+e] - mean) * rstd * gg[8+e] + bb[8+e]);
    }
    bf16x8* yp = (bf16x8*)(Y + base);
    yp[0] = o0; yp[1] = o1;
}

// ---------------- embedding: x = tok_emb[shifted] + pos_emb ----------------
// tg is already offset to this chunk's first batch; rows are chunk-local.
__global__ __launch_bounds__(256) void lam_embed(const int* __restrict__ tg,
                                                 const float* __restrict__ tok,
                                                 const float* __restrict__ pos,
                                                 bf16* __restrict__ X) {
    const int lane = threadIdx.x & 63;
    const long row = (long)blockIdx.x * 4 + (threadIdx.x >> 6);
    const int b = (int)(row >> 2), tt = (int)(row & 3);
    const int idx = (tt == 0) ? 16 : tg[b * 4 + tt - 1];
    const float4* tp = (const float4*)(tok + (long)idx * 1024 + lane * 16);
    const float4* pp = (const float4*)(pos + (long)tt * 1024 + lane * 16);
    bf16 o[16];
    #pragma unroll
    for (int q = 0; q < 4; ++q) {
        float4 a = tp[q], c = pp[q];
        o[q*4+0]=(bf16)(a.x+c.x); o[q*4+1]=(bf16)(a.y+c.y);
        o[q*4+2]=(bf16)(a.z+c.z); o[q*4+3]=(bf16)(a.w+c.w);
    }
    bf16x8 o0, o1;
    #pragma unroll
    for (int e = 0; e < 8; ++e) { o0[e] = o[e]; o1[e] = o[8+e]; }
    bf16x8* yp = (bf16x8*)(X + row * 1024 + lane * 16);
    yp[0] = o0; yp[1] = o1;
}

// ---------------- GEMM: C = epi(A @ W^T + bias)  (A: MxK, W: NxK row-major)
// EPI: 0 none, 1 gelu(exact), 2 relu, 3 residual(+optional broadcast R2)
template<int EPI>
__global__ __launch_bounds__(256) void lam_gemm(const bf16* __restrict__ A,
                                                const bf16* __restrict__ W,
                                                const float* __restrict__ bias,
                                                bf16* C, const bf16* R, const bf16* R2,
                                                int M, int N, int K) {
    __shared__ bf16 As[128 * 32];
    __shared__ bf16 Bs[128 * 32];
    const int t = threadIdx.x;
    const int lane = t & 63;
    const int wid = t >> 6;
    const int wr = wid >> 1, wc = wid & 1;
    const long bm = (long)blockIdx.x * 128;
    const long bn = (long)blockIdx.y * 128;

    const char* Ag = (const char*)(A + bm * K);
    const char* Wg = (const char*)(W + bn * K);
    const long rb0 = (long)(t >> 2) * (K * 2);
    const long rb1 = (long)((t >> 2) + 64) * (K * 2);
    const int cb = (t & 3) * 16;
    char* ldsA = (char*)As + wid * 1024;
    char* ldsB = (char*)Bs + wid * 1024;

    f32x4 acc[4][4] = {};

    for (int k0 = 0; k0 < K; k0 += 32) {
        const long kb = (long)k0 * 2 + cb;
        __syncthreads();
        gll16(Ag + rb0 + kb, ldsA);
        gll16(Ag + rb1 + kb, ldsA + 4096);
        gll16(Wg + rb0 + kb, ldsB);
        gll16(Wg + rb1 + kb, ldsB + 4096);
        __syncthreads();
        const int ko = (lane >> 4) * 8;
        const int ra = (wr * 64 + (lane & 15)) * 32 + ko;
        const int rbb = (wc * 64 + (lane & 15)) * 32 + ko;
        bf16x8 af[4], bfv[4];
        #pragma unroll
        for (int i = 0; i < 4; ++i) {
            af[i]  = *reinterpret_cast<const bf16x8*>(&As[ra  + i * 512]);
            bfv[i] = *reinterpret_cast<const bf16x8*>(&Bs[rbb + i * 512]);
        }
        #pragma unroll
        for (int i = 0; i < 4; ++i)
            #pragma unroll
            for (int j = 0; j < 4; ++j)
                acc[i][j] = __builtin_amdgcn_mfma_f32_16x16x32_bf16(af[i], bfv[j], acc[i][j], 0, 0, 0);
    }

    const int lr = (lane >> 4) * 4;
    const int lc = lane & 15;
    #pragma unroll
    for (int i = 0; i < 4; ++i) {
        const long row0 = bm + wr * 64 + i * 16 + lr;
        #pragma unroll
        for (int j = 0; j < 4; ++j) {
            const long col = bn + wc * 64 + j * 16 + lc;
            const float bv = bias[col];
            #pragma unroll
            for (int q = 0; q < 4; ++q) {
                const long row = row0 + q;
                float v = acc[i][j][q] + bv;
                const long idx = row * N + col;
                if (EPI == 1) v = 0.5f * v * (1.0f + erff(v * 0.70710678118654752f));
                if (EPI == 2) v = fmaxf(v, 0.0f);
                if (EPI == 3) {
                    v += (float)R[idx];
                    if (R2) v += (float)R2[(row >> 2) * N + col];
                }
                C[idx] = (bf16)v;
            }
        }
    }
}

// ---------------- self-attention, NT=4, one wave per (b,h), chunk-local ----------------
__global__ __launch_bounds__(256) void lam_attn(const bf16* __restrict__ qkv,
                                                bf16* __restrict__ O) {
    const int lane = threadIdx.x & 63;
    const long unit = (long)blockIdx.x * 4 + (threadIdx.x >> 6);
    const long rl = (unit >> 3) * 4;           // local row base
    const int h = (int)(unit & 7);
    const long base0 = rl * 3072 + h * 128 + lane * 2;
    float qf[4][2], kf[4][2], vf[4][2];
    #pragma unroll
    for (int tt = 0; tt < 4; ++tt) {
        const bf16* p = qkv + base0 + tt * 3072;
        bf16x2 qu = *(const bf16x2*)(p);
        bf16x2 ku = *(const bf16x2*)(p + 1024);
        bf16x2 vu = *(const bf16x2*)(p + 2048);
        qf[tt][0]=(float)qu[0]; qf[tt][1]=(float)qu[1];
        kf[tt][0]=(float)ku[0]; kf[tt][1]=(float)ku[1];
        vf[tt][0]=(float)vu[0]; vf[tt][1]=(float)vu[1];
    }
    float s[4][4];
    #pragma unroll
    for (int i = 0; i < 4; ++i)
        #pragma unroll
        for (int j = 0; j < 4; ++j)
            s[i][j] = (j <= i) ? (qf[i][0]*kf[j][0] + qf[i][1]*kf[j][1]) : 0.0f;
    #pragma unroll
    for (int m = 1; m < 64; m <<= 1)
        #pragma unroll
        for (int i = 0; i < 4; ++i)
            #pragma unroll
            for (int j = 0; j < 4; ++j)
                if (j <= i) s[i][j] += __shfl_xor(s[i][j], m);
    const float sc = 0.08838834764831845f;     // 1/sqrt(128)
    float a[4][4];
    #pragma unroll
    for (int i = 0; i < 4; ++i) {
        float mx = -1e30f;
        #pragma unroll
        for (int j = 0; j < 4; ++j) if (j <= i) mx = fmaxf(mx, s[i][j] * sc);
        float sum = 0.f;
        #pragma unroll
        for (int j = 0; j < 4; ++j) if (j <= i) { a[i][j] = expf(s[i][j]*sc - mx); sum += a[i][j]; }
        const float inv = 1.0f / sum;
        #pragma unroll
        for (int j = 0; j < 4; ++j) if (j <= i) a[i][j] *= inv;
    }
    #pragma unroll
    for (int i = 0; i < 4; ++i) {
        float o0 = 0.f, o1 = 0.f;
        #pragma unroll
        for (int j = 0; j < 4; ++j) if (j <= i) { o0 += a[i][j]*vf[j][0]; o1 += a[i][j]*vf[j][1]; }
        bf16x2 ov; ov[0] = (bf16)o0; ov[1] = (bf16)o1;
        *(bf16x2*)(O + (rl + i) * 1024 + h * 128 + lane * 2) = ov;
    }
}

// ---------------- logits: out = X @ Wout^T + b  (N=16, fp32 out) ----------------
__global__ __launch_bounds__(256) void lam_logits(const bf16* __restrict__ X,
                                                  const bf16* __restrict__ Wo,
                                                  const float* __restrict__ bo,
                                                  float* __restrict__ out) {
    __shared__ bf16 ws[16 * 1024];
    const int tid = threadIdx.x;
    for (int i = tid * 8; i < 16384; i += 2048)
        *(bf16x8*)(ws + i) = *(const bf16x8*)(Wo + i);
    __syncthreads();
    const long r = (long)blockIdx.x * 16 + (tid >> 4);
    const int j = tid & 15;
    const bf16* xr = X + r * 1024;
    const bf16* wr = ws + j * 1024;
    float acc = 0.f;
    for (int k = 0; k < 1024; k += 8) {
        bf16x8 xv = *(const bf16x8*)(xr + k);
        bf16x8 wv = *(const bf16x8*)(wr + k);
        #pragma unroll
        for (int e = 0; e < 8; ++e) acc += (float)xv[e] * (float)wv[e];
    }
    out[r * 16 + j] = acc + bo[j];
}

// =============================== host ===============================
extern "C" void kernel_launch(void* const* d_in, const int* in_sizes, int n_in,
                              void* d_out, int out_size, void* d_ws, size_t ws_size,
                              hipStream_t stream) {
    const float* context = (const float*)d_in[0];
    const int*   targets = (const int*)d_in[1];
    const float* tok_emb = (const float*)d_in[2];
    const float* pos_emb = (const float*)d_in[3];
    const float* cp_ln_g = (const float*)d_in[4];
    const float* cp_ln_b = (const float*)d_in[5];
    const float* cp_w    = (const float*)d_in[6];
    const float* cp_b    = (const float*)d_in[7];
    const float* sa_wq   = (const float*)d_in[8];
    const float* sa_bq   = (const float*)d_in[9];
    const float* sa_wk   = (const float*)d_in[10];
    const float* sa_bk   = (const float*)d_in[11];
    const float* sa_wv   = (const float*)d_in[12];
    const float* sa_bv   = (const float*)d_in[13];
    const float* sa_wo   = (const float*)d_in[14];
    const float* sa_bo   = (const float*)d_in[15];
    // ca_wq/bq (16,17), ca_wk/bk (18,19), ln2 (26,27): dead — kv len is 1
    const float* ca_wv   = (const float*)d_in[20];
    const float* ca_bv   = (const float*)d_in[21];
    const float* ca_wo   = (const float*)d_in[22];
    const float* ca_bo   = (const float*)d_in[23];
    const float* ln1_g   = (const float*)d_in[24];
    const float* ln1_b   = (const float*)d_in[25];
    const float* ln3_g   = (const float*)d_in[28];
    const float* ln3_b   = (const float*)d_in[29];
    const float* ff_w1   = (const float*)d_in[30];
    const float* ff_b1   = (const float*)d_in[31];
    const float* ff_w2   = (const float*)d_in[32];
    const float* ff_b2   = (const float*)d_in[33];
    const float* out_w   = (const float*)d_in[34];
    const float* out_b   = (const float*)d_in[35];

    char* ws = (char*)d_ws;
    size_t off = 0;
    auto take = [&](size_t bytes) -> char* {
        char* p = ws + off;
        off += (bytes + 255) & ~(size_t)255;
        return p;
    };
    // ---- persistent: bf16 weights (22.1 MB) + ca_out (32 MB) ----
    bf16*  Wcp  = (bf16*)take((size_t)1048576 * 2);
    bf16*  Wcav = (bf16*)take((size_t)1048576 * 2);
    bf16*  Wcao = (bf16*)take((size_t)1048576 * 2);
    bf16*  Wqkv = (bf16*)take((size_t)3145728 * 2);
    bf16*  Wsao = (bf16*)take((size_t)1048576 * 2);
    bf16*  Wff1 = (bf16*)take((size_t)2097152 * 2);
    bf16*  Wff2 = (bf16*)take((size_t)2097152 * 2);
    bf16*  Wout = (bf16*)take((size_t)16384 * 2);
    float* bqkv = (float*)take((size_t)3072 * 4);
    bf16*  caO  = (bf16*)take((size_t)16384 * 1024 * 2);

    // ---- adaptive chunk pool: x, h (rows*1024), q3 (rows*3072), bf16 ----
    long chunk_rows = 65536;
    while (chunk_rows > 512 &&
           off + (size_t)chunk_rows * 10240 > ws_size)
        chunk_rows >>= 1;
    bf16* xb = (bf16*)take((size_t)chunk_rows * 1024 * 2);
    bf16* hb = (bf16*)take((size_t)chunk_rows * 1024 * 2);
    bf16* q3 = (bf16*)take((size_t)chunk_rows * 3072 * 2);
    const long nchunks = 65536 / chunk_rows;

    // --- weights -> bf16 (packed qkv) ---
    lam_cvt<<<512, 256, 0, stream>>>(cp_w, Wcp, 1048576);
    lam_cvt<<<512, 256, 0, stream>>>(ca_wv, Wcav, 1048576);
    lam_cvt<<<512, 256, 0, stream>>>(ca_wo, Wcao, 1048576);
    lam_cvt<<<512, 256, 0, stream>>>(sa_wq, Wqkv, 1048576);
    lam_cvt<<<512, 256, 0, stream>>>(sa_wk, Wqkv + 1048576, 1048576);
    lam_cvt<<<512, 256, 0, stream>>>(sa_wv, Wqkv + 2097152, 1048576);
    lam_cvt<<<512, 256, 0, stream>>>(sa_wo, Wsao, 1048576);
    lam_cvt<<<1024, 256, 0, stream>>>(ff_w1, Wff1, 2097152);
    lam_cvt<<<1024, 256, 0, stream>>>(ff_w2, Wff2, 2097152);
    lam_cvt<<<8, 256, 0, stream>>>(out_w, Wout, 16384);
    lam_packb<<<12, 256, 0, stream>>>(sa_bq, sa_bk, sa_bv, bqkv);

    // --- context path (chunked through the same pool):
    //     caO = ((gelu(LN(ctx)@cp_w^T+cp_b)) @ ca_wv^T + bv) @ ca_wo^T + bo ---
    const long cm = (chunk_rows < 16384) ? chunk_rows : 16384;
    for (long r0 = 0; r0 < 16384; r0 += cm) {
        lam_ln<true><<<cm / 4, 256, 0, stream>>>(context + r0 * 1024, cp_ln_g, cp_ln_b, xb);
        lam_gemm<1><<<dim3(cm / 128, 8), 256, 0, stream>>>(xb, Wcp,  cp_b,  hb, nullptr, nullptr, (int)cm, 1024, 1024);
        lam_gemm<0><<<dim3(cm / 128, 8), 256, 0, stream>>>(hb, Wcav, ca_bv, xb, nullptr, nullptr, (int)cm, 1024, 1024);
        lam_gemm<0><<<dim3(cm / 128, 8), 256, 0, stream>>>(xb, Wcao, ca_bo, caO + r0 * 1024, nullptr, nullptr, (int)cm, 1024, 1024);
    }

    // --- decoder, chunked over batches ---
    for (long c = 0; c < nchunks; ++c) {
        const long r0 = c * chunk_rows;       // global row offset
        const long b0 = r0 >> 2;              // global batch offset
        lam_embed<<<chunk_rows / 4, 256, 0, stream>>>(targets + b0 * 4, tok_emb, pos_emb, xb);
        lam_ln<false><<<chunk_rows / 4, 256, 0, stream>>>(xb, ln1_g, ln1_b, hb);
        lam_gemm<0><<<dim3(chunk_rows / 128, 24), 256, 0, stream>>>(
            hb, Wqkv, bqkv, q3, nullptr, nullptr, (int)chunk_rows, 3072, 1024);
        lam_attn<<<chunk_rows / 2, 256, 0, stream>>>(q3, hb);
        // x = x0 + attn@wo^T + bo + caO(broadcast over NT)
        lam_gemm<3><<<dim3(chunk_rows / 128, 8), 256, 0, stream>>>(
            hb, Wsao, sa_bo, xb, xb, caO + b0 * 1024, (int)chunk_rows, 1024, 1024);
        lam_ln<false><<<chunk_rows / 4, 256, 0, stream>>>(xb, ln3_g, ln3_b, hb);
        lam_gemm<2><<<dim3(chunk_rows / 128, 16), 256, 0, stream>>>(
            hb, Wff1, ff_b1, q3, nullptr, nullptr, (int)chunk_rows, 2048, 1024);
        lam_gemm<3><<<dim3(chunk_rows / 128, 8), 256, 0, stream>>>(
            q3, Wff2, ff_b2, xb, xb, nullptr, (int)chunk_rows, 1024, 2048);
        lam_logits<<<chunk_rows / 16, 256, 0, stream>>>(xb, Wout, out_b, (float*)d_out + r0 * 16);
    }

    (void)in_sizes; (void)n_in; (void)out_size;
}

// Round 3
// 1917.787 us; speedup vs baseline: 1.3420x; 1.3420x over previous
//
#include <hip/hip_runtime.h>
#include <math.h>

typedef __bf16 bf16;
typedef float f32x4 __attribute__((ext_vector_type(4)));
typedef bf16 bf16x8 __attribute__((ext_vector_type(8)));
typedef bf16 bf16x2 __attribute__((ext_vector_type(2)));

// async global->LDS, 16B per lane; lds base must be wave-uniform
__device__ __forceinline__ void gll16(const void* g, void* l) {
    __builtin_amdgcn_global_load_lds(
        (const __attribute__((address_space(1))) void*)g,
        (__attribute__((address_space(3))) void*)l, 16, 0, 0);
}

// ---------------- fp32 -> bf16 convert (weights) ----------------
__global__ __launch_bounds__(256) void lam_cvt(const float* __restrict__ s,
                                               bf16* __restrict__ d, int n) {
    int i = (blockIdx.x * 256 + threadIdx.x) * 8;
    if (i >= n) return;
    float4 a = *(const float4*)(s + i);
    float4 b = *(const float4*)(s + i + 4);
    bf16x8 o;
    o[0] = (bf16)a.x; o[1] = (bf16)a.y; o[2] = (bf16)a.z; o[3] = (bf16)a.w;
    o[4] = (bf16)b.x; o[5] = (bf16)b.y; o[6] = (bf16)b.z; o[7] = (bf16)b.w;
    *(bf16x8*)(d + i) = o;
}

__global__ __launch_bounds__(256) void lam_packb(const float* __restrict__ q,
                                                 const float* __restrict__ k,
                                                 const float* __restrict__ v,
                                                 float* __restrict__ dst) {
    int i = blockIdx.x * 256 + threadIdx.x;
    if (i < 1024) dst[i] = q[i];
    else if (i < 2048) dst[i] = k[i - 1024];
    else if (i < 3072) dst[i] = v[i - 2048];
}

// ---------------- LayerNorm: one wave per 1024-elem row ----------------
template<bool FP32IN>
__global__ __launch_bounds__(256) void lam_ln(const void* __restrict__ Xv,
                                              const float* __restrict__ g,
                                              const float* __restrict__ bta,
                                              bf16* __restrict__ Y) {
    const int lane = threadIdx.x & 63;
    const long row = (long)blockIdx.x * 4 + (threadIdx.x >> 6);
    const long base = row * 1024 + lane * 16;
    float v[16];
    if (FP32IN) {
        const float4* p = (const float4*)((const float*)Xv + base);
        #pragma unroll
        for (int q = 0; q < 4; ++q) {
            float4 f = p[q];
            v[q*4+0]=f.x; v[q*4+1]=f.y; v[q*4+2]=f.z; v[q*4+3]=f.w;
        }
    } else {
        const bf16x8* p = (const bf16x8*)((const bf16*)Xv + base);
        #pragma unroll
        for (int q = 0; q < 2; ++q) {
            bf16x8 u = p[q];
            #pragma unroll
            for (int e = 0; e < 8; ++e) v[q*8+e] = (float)u[e];
        }
    }
    float s = 0.f;
    #pragma unroll
    for (int e = 0; e < 16; ++e) s += v[e];
    #pragma unroll
    for (int m = 32; m >= 1; m >>= 1) s += __shfl_xor(s, m);
    const float mean = s * (1.0f / 1024.0f);
    float vs = 0.f;
    #pragma unroll
    for (int e = 0; e < 16; ++e) { float d = v[e] - mean; vs += d * d; }
    #pragma unroll
    for (int m = 32; m >= 1; m >>= 1) vs += __shfl_xor(vs, m);
    const float rstd = rsqrtf(vs * (1.0f / 1024.0f) + 1e-5f);
    const int kb = lane * 16;
    float gg[16], bb[16];
    const float4* gp = (const float4*)(g + kb);
    const float4* bp = (const float4*)(bta + kb);
    #pragma unroll
    for (int q = 0; q < 4; ++q) {
        float4 a = gp[q], c = bp[q];
        gg[q*4+0]=a.x; gg[q*4+1]=a.y; gg[q*4+2]=a.z; gg[q*4+3]=a.w;
        bb[q*4+0]=c.x; bb[q*4+1]=c.y; bb[q*4+2]=c.z; bb[q*4+3]=c.w;
    }
    bf16x8 o0, o1;
    #pragma unroll
    for (int e = 0; e < 8; ++e) {
        o0[e] = (bf16)((v[e]   - mean) * rstd * gg[e]   + bb[e]);
        o1[e] = (bf16)((v[8+e] - mean) * rstd * gg[8+e] + bb[8+e]);
    }
    bf16x8* yp = (bf16x8*)(Y + base);
    yp[0] = o0; yp[1] = o1;
}

// ---------------- fused embedding + LN1: X = tok[shift]+pos, Y = LN(X) ----------------
__global__ __launch_bounds__(256) void lam_embed_ln(const int* __restrict__ tg,
                                                    const float* __restrict__ tok,
                                                    const float* __restrict__ pos,
                                                    const float* __restrict__ g,
                                                    const float* __restrict__ bta,
                                                    bf16* __restrict__ X,
                                                    bf16* __restrict__ Y) {
    const int lane = threadIdx.x & 63;
    const long row = (long)blockIdx.x * 4 + (threadIdx.x >> 6);
    const int b = (int)(row >> 2), tt = (int)(row & 3);
    const int idx = (tt == 0) ? 16 : tg[b * 4 + tt - 1];
    float v[16];
    const float4* tp = (const float4*)(tok + (long)idx * 1024 + lane * 16);
    const float4* pp = (const float4*)(pos + (long)tt * 1024 + lane * 16);
    #pragma unroll
    for (int q = 0; q < 4; ++q) {
        float4 a = tp[q], c = pp[q];
        v[q*4+0]=a.x+c.x; v[q*4+1]=a.y+c.y; v[q*4+2]=a.z+c.z; v[q*4+3]=a.w+c.w;
    }
    bf16x8 x0, x1;
    #pragma unroll
    for (int e = 0; e < 8; ++e) { x0[e] = (bf16)v[e]; x1[e] = (bf16)v[8+e]; }
    bf16x8* xp = (bf16x8*)(X + row * 1024 + lane * 16);
    xp[0] = x0; xp[1] = x1;

    float s = 0.f;
    #pragma unroll
    for (int e = 0; e < 16; ++e) s += v[e];
    #pragma unroll
    for (int m = 32; m >= 1; m >>= 1) s += __shfl_xor(s, m);
    const float mean = s * (1.0f / 1024.0f);
    float vs = 0.f;
    #pragma unroll
    for (int e = 0; e < 16; ++e) { float d = v[e] - mean; vs += d * d; }
    #pragma unroll
    for (int m = 32; m >= 1; m >>= 1) vs += __shfl_xor(vs, m);
    const float rstd = rsqrtf(vs * (1.0f / 1024.0f) + 1e-5f);
    const int kb = lane * 16;
    float gg[16], bb[16];
    const float4* gp = (const float4*)(g + kb);
    const float4* bp = (const float4*)(bta + kb);
    #pragma unroll
    for (int q = 0; q < 4; ++q) {
        float4 a = gp[q], c = bp[q];
        gg[q*4+0]=a.x; gg[q*4+1]=a.y; gg[q*4+2]=a.z; gg[q*4+3]=a.w;
        bb[q*4+0]=c.x; bb[q*4+1]=c.y; bb[q*4+2]=c.z; bb[q*4+3]=c.w;
    }
    bf16x8 o0, o1;
    #pragma unroll
    for (int e = 0; e < 8; ++e) {
        o0[e] = (bf16)((v[e]   - mean) * rstd * gg[e]   + bb[e]);
        o1[e] = (bf16)((v[8+e] - mean) * rstd * gg[8+e] + bb[8+e]);
    }
    bf16x8* yp = (bf16x8*)(Y + row * 1024 + lane * 16);
    yp[0] = o0; yp[1] = o1;
}

// ---------------- GEMM v2: TMx256 tile, BK=64, 8 waves, 2-phase dbuf ----------------
// C = epi(A @ W^T + bias); A: MxK, W: NxK, both bf16 row-major.
// EPI: 0 none, 1 gelu(exact), 2 relu, 3 residual(+optional broadcast R2)
// LDS swizzle: 16B-block index ^= (row&7); both staged (pre-swizzled global
// source for linear global_load_lds dest) and read with the same involution.
template<int EPI, int TM>
__global__ __launch_bounds__(512, 2) void lam_gemm2(const bf16* __restrict__ A,
                                                    const bf16* __restrict__ W,
                                                    const float* __restrict__ bias,
                                                    bf16* C, const bf16* R, const bf16* R2,
                                                    int M, int N, int K) {
    constexpr int AR    = TM / 64;          // A staging rounds (8KB each)
    constexpr int ABYTE = TM * 128;         // A region bytes per buffer
    constexpr int BUFB  = ABYTE + 32768;    // per-buffer bytes (A + B[256][64])
    constexpr int IM    = TM / 32;          // 16-row A-fragments per wave
    __shared__ char lds[2 * BUFB];

    const int t    = threadIdx.x;
    const int lane = t & 63;
    const int wid  = t >> 6;
    const int wm   = wid >> 2;              // 0..1
    const int wn   = wid & 3;               // 0..3

    // ---- bijective XCD-chunked remap; grid = (N/256 [fastest], M/TM) ----
    const int gx   = gridDim.x;
    const int nwg  = gx * gridDim.y;
    const int orig = blockIdx.y * gx + blockIdx.x;
    const int q8 = nwg >> 3, r8 = nwg & 7;
    const int xcd = orig & 7, i8 = orig >> 3;
    const int wg  = (xcd < r8 ? xcd * (q8 + 1) : r8 * (q8 + 1) + (xcd - r8) * q8) + i8;
    const long bm = (long)(wg / gx) * TM;
    const long bn = (long)(wg % gx) * 256;

    // ---- staging addresses (pre-swizzled global source) ----
    const long rs = (long)K * 2;
    const char* Ag = (const char*)A + bm * rs;
    const char* Wg = (const char*)W + bn * rs;
    const int  srow = t >> 3;                                    // 0..63
    const int  scol = (((t & 7) ^ ((t >> 3) & 7)) << 4);         // swizzled 16B block
    const long g0   = (long)srow * rs + scol;

    // ---- ds_read offsets ----
    const int xorq = (lane & 7) << 4;
    const int arow = wm * (TM / 2) + (lane & 15);
    const int brow = wn * 64 + (lane & 15);
    const int kq   = (lane >> 4) * 16;

    f32x4 acc[IM][4] = {};

    auto STAGE = [&](int buf, long kbyte) {
        char* base = lds + buf * BUFB + wid * 1024;
        const char* ga = Ag + g0 + kbyte;
        const char* gb = Wg + g0 + kbyte;
        #pragma unroll
        for (int r = 0; r < AR; ++r)
            gll16(ga + (long)r * 64 * rs, base + r * 8192);
        #pragma unroll
        for (int r = 0; r < 4; ++r)
            gll16(gb + (long)r * 64 * rs, base + ABYTE + r * 8192);
    };

    STAGE(0, 0);
    asm volatile("s_waitcnt vmcnt(0)" ::: "memory");
    __syncthreads();

    const int NT = K >> 6;
    int cur = 0;
    for (int kt = 0; kt < NT; ++kt) {
        if (kt + 1 < NT) STAGE(cur ^ 1, (long)(kt + 1) * 128);
        const char* ab = lds + cur * BUFB;
        const char* bb = ab + ABYTE;
        #pragma unroll
        for (int ks = 0; ks < 2; ++ks) {
            const int kc = kq + ks * 64;
            bf16x8 bv[4];
            #pragma unroll
            for (int j = 0; j < 4; ++j) {
                const int x = (brow + j * 16) * 128 + kc;
                bv[j] = *(const bf16x8*)(bb + (x ^ xorq));
            }
            #pragma unroll
            for (int i = 0; i < IM; ++i) {
                const int x = (arow + i * 16) * 128 + kc;
                bf16x8 av = *(const bf16x8*)(ab + (x ^ xorq));
                #pragma unroll
                for (int j = 0; j < 4; ++j)
                    acc[i][j] = __builtin_amdgcn_mfma_f32_16x16x32_bf16(av, bv[j], acc[i][j], 0, 0, 0);
            }
        }
        asm volatile("s_waitcnt vmcnt(0)" ::: "memory");
        __syncthreads();
        cur ^= 1;
    }

    // ---- epilogue ----
    const int lr = (lane >> 4) * 4;
    const int lc = lane & 15;
    #pragma unroll
    for (int i = 0; i < IM; ++i) {
        const long row0 = bm + wm * (TM / 2) + i * 16 + lr;
        #pragma unroll
        for (int j = 0; j < 4; ++j) {
            const long col = bn + wn * 64 + j * 16 + lc;
            const float bvs = bias[col];
            #pragma unroll
            for (int qq = 0; qq < 4; ++qq) {
                const long row = row0 + qq;
                float v = acc[i][j][qq] + bvs;
                const long idx = row * N + col;
                if (EPI == 1) v = 0.5f * v * (1.0f + erff(v * 0.70710678118654752f));
                if (EPI == 2) v = fmaxf(v, 0.0f);
                if (EPI == 3) {
                    v += (float)R[idx];
                    if (R2) v += (float)R2[(row >> 2) * N + col];
                }
                C[idx] = (bf16)v;
            }
        }
    }
}

static void gemm2(int epi, const bf16* A, const bf16* W, const float* bias, bf16* C,
                  const bf16* R, const bf16* R2, int M, int N, int K, hipStream_t s) {
    const long n256 = (long)(M >> 8) * (N >> 8);
    if (n256 >= 256 && (M & 255) == 0) {
        dim3 grid(N / 256, M / 256);
        switch (epi) {
            case 0: lam_gemm2<0,256><<<grid,512,0,s>>>(A,W,bias,C,R,R2,M,N,K); break;
            case 1: lam_gemm2<1,256><<<grid,512,0,s>>>(A,W,bias,C,R,R2,M,N,K); break;
            case 2: lam_gemm2<2,256><<<grid,512,0,s>>>(A,W,bias,C,R,R2,M,N,K); break;
            default:lam_gemm2<3,256><<<grid,512,0,s>>>(A,W,bias,C,R,R2,M,N,K); break;
        }
    } else {
        dim3 grid(N / 256, M / 128);
        switch (epi) {
            case 0: lam_gemm2<0,128><<<grid,512,0,s>>>(A,W,bias,C,R,R2,M,N,K); break;
            case 1: lam_gemm2<1,128><<<grid,512,0,s>>>(A,W,bias,C,R,R2,M,N,K); break;
            case 2: lam_gemm2<2,128><<<grid,512,0,s>>>(A,W,bias,C,R,R2,M,N,K); break;
            default:lam_gemm2<3,128><<<grid,512,0,s>>>(A,W,bias,C,R,R2,M,N,K); break;
        }
    }
}

// ---------------- self-attention, NT=4, one wave per (b,h), chunk-local ----------------
__global__ __launch_bounds__(256) void lam_attn(const bf16* __restrict__ qkv,
                                                bf16* __restrict__ O) {
    const int lane = threadIdx.x & 63;
    const long unit = (long)blockIdx.x * 4 + (threadIdx.x >> 6);
    const long rl = (unit >> 3) * 4;           // local row base
    const int h = (int)(unit & 7);
    const long base0 = rl * 3072 + h * 128 + lane * 2;
    float qf[4][2], kf[4][2], vf[4][2];
    #pragma unroll
    for (int tt = 0; tt < 4; ++tt) {
        const bf16* p = qkv + base0 + tt * 3072;
        bf16x2 qu = *(const bf16x2*)(p);
        bf16x2 ku = *(const bf16x2*)(p + 1024);
        bf16x2 vu = *(const bf16x2*)(p + 2048);
        qf[tt][0]=(float)qu[0]; qf[tt][1]=(float)qu[1];
        kf[tt][0]=(float)ku[0]; kf[tt][1]=(float)ku[1];
        vf[tt][0]=(float)vu[0]; vf[tt][1]=(float)vu[1];
    }
    float s[4][4];
    #pragma unroll
    for (int i = 0; i < 4; ++i)
        #pragma unroll
        for (int j = 0; j < 4; ++j)
            s[i][j] = (j <= i) ? (qf[i][0]*kf[j][0] + qf[i][1]*kf[j][1]) : 0.0f;
    #pragma unroll
    for (int m = 1; m < 64; m <<= 1)
        #pragma unroll
        for (int i = 0; i < 4; ++i)
            #pragma unroll
            for (int j = 0; j < 4; ++j)
                if (j <= i) s[i][j] += __shfl_xor(s[i][j], m);
    const float sc = 0.08838834764831845f;     // 1/sqrt(128)
    float a[4][4];
    #pragma unroll
    for (int i = 0; i < 4; ++i) {
        float mx = -1e30f;
        #pragma unroll
        for (int j = 0; j < 4; ++j) if (j <= i) mx = fmaxf(mx, s[i][j] * sc);
        float sum = 0.f;
        #pragma unroll
        for (int j = 0; j < 4; ++j) if (j <= i) { a[i][j] = expf(s[i][j]*sc - mx); sum += a[i][j]; }
        const float inv = 1.0f / sum;
        #pragma unroll
        for (int j = 0; j < 4; ++j) if (j <= i) a[i][j] *= inv;
    }
    #pragma unroll
    for (int i = 0; i < 4; ++i) {
        float o0 = 0.f, o1 = 0.f;
        #pragma unroll
        for (int j = 0; j < 4; ++j) if (j <= i) { o0 += a[i][j]*vf[j][0]; o1 += a[i][j]*vf[j][1]; }
        bf16x2 ov; ov[0] = (bf16)o0; ov[1] = (bf16)o1;
        *(bf16x2*)(O + (rl + i) * 1024 + h * 128 + lane * 2) = ov;
    }
}

// ---------------- logits: out = X @ Wout^T + b  (N=16, fp32 out) ----------------
__global__ __launch_bounds__(256) void lam_logits(const bf16* __restrict__ X,
                                                  const bf16* __restrict__ Wo,
                                                  const float* __restrict__ bo,
                                                  float* __restrict__ out) {
    __shared__ bf16 ws[16 * 1024];
    const int tid = threadIdx.x;
    for (int i = tid * 8; i < 16384; i += 2048)
        *(bf16x8*)(ws + i) = *(const bf16x8*)(Wo + i);
    __syncthreads();
    const long r = (long)blockIdx.x * 16 + (tid >> 4);
    const int j = tid & 15;
    const bf16* xr = X + r * 1024;
    const bf16* wr = ws + j * 1024;
    float acc = 0.f;
    for (int k = 0; k < 1024; k += 8) {
        bf16x8 xv = *(const bf16x8*)(xr + k);
        bf16x8 wv = *(const bf16x8*)(wr + k);
        #pragma unroll
        for (int e = 0; e < 8; ++e) acc += (float)xv[e] * (float)wv[e];
    }
    out[r * 16 + j] = acc + bo[j];
}

// =============================== host ===============================
extern "C" void kernel_launch(void* const* d_in, const int* in_sizes, int n_in,
                              void* d_out, int out_size, void* d_ws, size_t ws_size,
                              hipStream_t stream) {
    const float* context = (const float*)d_in[0];
    const int*   targets = (const int*)d_in[1];
    const float* tok_emb = (const float*)d_in[2];
    const float* pos_emb = (const float*)d_in[3];
    const float* cp_ln_g = (const float*)d_in[4];
    const float* cp_ln_b = (const float*)d_in[5];
    const float* cp_w    = (const float*)d_in[6];
    const float* cp_b    = (const float*)d_in[7];
    const float* sa_wq   = (const float*)d_in[8];
    const float* sa_bq   = (const float*)d_in[9];
    const float* sa_wk   = (const float*)d_in[10];
    const float* sa_bk   = (const float*)d_in[11];
    const float* sa_wv   = (const float*)d_in[12];
    const float* sa_bv   = (const float*)d_in[13];
    const float* sa_wo   = (const float*)d_in[14];
    const float* sa_bo   = (const float*)d_in[15];
    // ca_wq/bq (16,17), ca_wk/bk (18,19), ln2 (26,27): dead — kv len is 1
    const float* ca_wv   = (const float*)d_in[20];
    const float* ca_bv   = (const float*)d_in[21];
    const float* ca_wo   = (const float*)d_in[22];
    const float* ca_bo   = (const float*)d_in[23];
    const float* ln1_g   = (const float*)d_in[24];
    const float* ln1_b   = (const float*)d_in[25];
    const float* ln3_g   = (const float*)d_in[28];
    const float* ln3_b   = (const float*)d_in[29];
    const float* ff_w1   = (const float*)d_in[30];
    const float* ff_b1   = (const float*)d_in[31];
    const float* ff_w2   = (const float*)d_in[32];
    const float* ff_b2   = (const float*)d_in[33];
    const float* out_w   = (const float*)d_in[34];
    const float* out_b   = (const float*)d_in[35];

    char* ws = (char*)d_ws;
    size_t off = 0;
    auto take = [&](size_t bytes) -> char* {
        char* p = ws + off;
        off += (bytes + 255) & ~(size_t)255;
        return p;
    };
    // ---- persistent: bf16 weights (22.1 MB) + ca_out (32 MB) ----
    bf16*  Wcp  = (bf16*)take((size_t)1048576 * 2);
    bf16*  Wcav = (bf16*)take((size_t)1048576 * 2);
    bf16*  Wcao = (bf16*)take((size_t)1048576 * 2);
    bf16*  Wqkv = (bf16*)take((size_t)3145728 * 2);
    bf16*  Wsao = (bf16*)take((size_t)1048576 * 2);
    bf16*  Wff1 = (bf16*)take((size_t)2097152 * 2);
    bf16*  Wff2 = (bf16*)take((size_t)2097152 * 2);
    bf16*  Wout = (bf16*)take((size_t)16384 * 2);
    float* bqkv = (float*)take((size_t)3072 * 4);
    bf16*  caO  = (bf16*)take((size_t)16384 * 1024 * 2);

    // ---- adaptive chunk pool: x, h (rows*1024), q3 (rows*3072), bf16 ----
    long chunk_rows = 65536;
    while (chunk_rows > 512 &&
           off + (size_t)chunk_rows * 10240 > ws_size)
        chunk_rows >>= 1;
    bf16* xb = (bf16*)take((size_t)chunk_rows * 1024 * 2);
    bf16* hb = (bf16*)take((size_t)chunk_rows * 1024 * 2);
    bf16* q3 = (bf16*)take((size_t)chunk_rows * 3072 * 2);
    const long nchunks = 65536 / chunk_rows;

    // --- weights -> bf16 (packed qkv) ---
    lam_cvt<<<512, 256, 0, stream>>>(cp_w, Wcp, 1048576);
    lam_cvt<<<512, 256, 0, stream>>>(ca_wv, Wcav, 1048576);
    lam_cvt<<<512, 256, 0, stream>>>(ca_wo, Wcao, 1048576);
    lam_cvt<<<512, 256, 0, stream>>>(sa_wq, Wqkv, 1048576);
    lam_cvt<<<512, 256, 0, stream>>>(sa_wk, Wqkv + 1048576, 1048576);
    lam_cvt<<<512, 256, 0, stream>>>(sa_wv, Wqkv + 2097152, 1048576);
    lam_cvt<<<512, 256, 0, stream>>>(sa_wo, Wsao, 1048576);
    lam_cvt<<<1024, 256, 0, stream>>>(ff_w1, Wff1, 2097152);
    lam_cvt<<<1024, 256, 0, stream>>>(ff_w2, Wff2, 2097152);
    lam_cvt<<<8, 256, 0, stream>>>(out_w, Wout, 16384);
    lam_packb<<<12, 256, 0, stream>>>(sa_bq, sa_bk, sa_bv, bqkv);

    // --- context path (chunked through the same pool):
    //     caO = ((gelu(LN(ctx)@cp_w^T+cp_b)) @ ca_wv^T + bv) @ ca_wo^T + bo ---
    const long cm = (chunk_rows < 16384) ? chunk_rows : 16384;
    for (long r0 = 0; r0 < 16384; r0 += cm) {
        lam_ln<true><<<cm / 4, 256, 0, stream>>>(context + r0 * 1024, cp_ln_g, cp_ln_b, xb);
        gemm2(1, xb, Wcp,  cp_b,  hb, nullptr, nullptr, (int)cm, 1024, 1024, stream);
        gemm2(0, hb, Wcav, ca_bv, xb, nullptr, nullptr, (int)cm, 1024, 1024, stream);
        gemm2(0, xb, Wcao, ca_bo, caO + r0 * 1024, nullptr, nullptr, (int)cm, 1024, 1024, stream);
    }

    // --- decoder, chunked over batches ---
    for (long c = 0; c < nchunks; ++c) {
        const long r0 = c * chunk_rows;       // global row offset
        const long b0 = r0 >> 2;              // global batch offset
        lam_embed_ln<<<chunk_rows / 4, 256, 0, stream>>>(targets + b0 * 4, tok_emb, pos_emb,
                                                         ln1_g, ln1_b, xb, hb);
        gemm2(0, hb, Wqkv, bqkv, q3, nullptr, nullptr, (int)chunk_rows, 3072, 1024, stream);
        lam_attn<<<chunk_rows / 2, 256, 0, stream>>>(q3, hb);
        // x = x0 + attn@wo^T + bo + caO(broadcast over NT)
        gemm2(3, hb, Wsao, sa_bo, xb, xb, caO + b0 * 1024, (int)chunk_rows, 1024, 1024, stream);
        lam_ln<false><<<chunk_rows / 4, 256, 0, stream>>>(xb, ln3_g, ln3_b, hb);
        gemm2(2, hb, Wff1, ff_b1, q3, nullptr, nullptr, (int)chunk_rows, 2048, 1024, stream);
        gemm2(3, q3, Wff2, ff_b2, xb, xb, nullptr, (int)chunk_rows, 1024, 2048, stream);
        lam_logits<<<chunk_rows / 16, 256, 0, stream>>>(xb, Wout, out_b, (float*)d_out + r0 * 16);
    }

    (void)in_sizes; (void)n_in; (void)out_size;
}